// Round 4
// baseline (131.717 us; speedup 1.0000x reference)
//
#include <hip/hip_runtime.h>
#include <stdint.h>

// VQ-VAE vector quantizer, MI355X — 2 blocks/CU for cross-block phase overlap.
// z: (32, 256, 32, 32) fp32 ; embedding: (1024, 256) fp32
// out: [0, 8388608) quant_z (N,C,H,W) ; [8388608] vq_loss ; [8388609] commit_loss
//
//   argmin_k ||z-e_k||^2 = argmin_k ( ||e_k||^2 - 2 z.e_k )   [bf16 MFMA scores]
//   vq_loss = (sum_m (||z_m||^2 + s_min(m))) / (M*C), commit = 0.25*vq_loss
//
// Round-4: 512 blocks x 256 thr (4 waves), 64 z-rows/block, LDS 71.9 KB ->
// TWO independent blocks per CU. Serial phases (HBM prologue / LDS+MFMA main
// loop / HBM gather epilogue) of co-resident blocks overlap (m114 mechanism);
// rounds 0-3 ran 1 block/CU = single lockstep barrier domain, no overlap.

#define CDIM  256

// ws byte offsets
#define WS_EB     16777216u    // bf16[1024][256] row-major (512 KB)
#define WS_ENORM  17301504u    // f32[1024]
#define WS_CNT    17436672u    // u32 completion counter
#define WS_LOSS   19664896u    // f32

// LDS byte offsets (dynamic shared, 71936 total -> 2 blocks/CU)
#define L_ZS     0u            // bf16 [64 rows][256 c], XOR-granule swizzle (32768)
#define L_ES     32768u        // bf16 [2][32 codes][256 c], swizzled, double buffer
#define L_TILEF  49152u        // f32[32][66] transpose scratch (aliases es buf1;
                               //   tile1 staged into buf1 only at main-loop tile 0)
#define L_ENORM  65536u        // f32[1024]
#define L_ZNP    69632u        // f32[256]
#define L_CAND   70656u        // float2[128]
#define L_IDX    71680u        // i32[64]
#define LDS_TOTAL 71936
#define GT_STRIDE 67           // gather tile f32[128 c][67] aliased at 0 (34304 B)

typedef __attribute__((ext_vector_type(8))) short bf16x8;
typedef __attribute__((ext_vector_type(4))) float f32x4;

__device__ inline unsigned short f2bf(float f) {
  uint32_t u = __float_as_uint(f);
  return (unsigned short)((u + 0x7FFFu + ((u >> 16) & 1u)) >> 16);
}

__device__ inline void load16(const void* g, void* l) {
  __builtin_amdgcn_global_load_lds((const __attribute__((address_space(1))) void*)g,
                                   (__attribute__((address_space(3))) void*)l, 16, 0, 0);
}

// E -> bf16 Eb (row-major) + eNorm ; zero loss + counter. 256 blocks x 256 thr.
__global__ void vq_prep_e(const float* __restrict__ E, char* __restrict__ ws) {
  const int w = threadIdx.x >> 6, l = threadIdx.x & 63;
  const int row = blockIdx.x * 4 + w;
  const float4 v = *(const float4*)(E + (size_t)row * CDIM + l * 4);
  ushort4 b;
  b.x = f2bf(v.x); b.y = f2bf(v.y); b.z = f2bf(v.z); b.w = f2bf(v.w);
  *(ushort4*)(ws + WS_EB + (size_t)row * 512 + l * 8) = b;
  float s = v.x * v.x + v.y * v.y + v.z * v.z + v.w * v.w;
  #pragma unroll
  for (int m = 32; m >= 1; m >>= 1) s += __shfl_xor(s, m);
  if (l == 0) ((float*)(ws + WS_ENORM))[row] = s;
  if (blockIdx.x == 0 && threadIdx.x == 0) {
    *((float*)(ws + WS_LOSS)) = 0.f;
    *((unsigned*)(ws + WS_CNT)) = 0u;
  }
}

// 512 blocks x 256 thr: 64 z-rows resident; 1024 codes streamed through LDS;
// argmin + loss + fused quant_z gather + last-block loss finalize.
__global__ __launch_bounds__(256, 2)
void vq_main(const float* __restrict__ z, const float* __restrict__ E,
             char* __restrict__ ws, float* __restrict__ out) {
  extern __shared__ char lds[];
  unsigned short* zs = (unsigned short*)(lds + L_ZS);
  char* esb          = lds + L_ES;
  float* tileF       = (float*)(lds + L_TILEF);
  float* eNormS      = (float*)(lds + L_ENORM);
  float* znPart      = (float*)(lds + L_ZNP);
  float2* cand       = (float2*)(lds + L_CAND);
  int* idxS          = (int*)(lds + L_IDX);
  float* gtile       = (float*)(lds);          // epilogue, aliases zs+es (dead)

  const int t = threadIdx.x, w = t >> 6, l = t & 63;
  const int mt = blockIdx.x;                   // 0..511
  const int n = mt >> 4, hw0 = (mt & 15) << 6;
  const char* Eb = ws + WS_EB;

  // per-thread staging source offsets for one 32-code es tile (swizzle baked in)
  int srcOff[4];
  #pragma unroll
  for (int i = 0; i < 4; ++i) {
    const int j = (i * 4 + w) * 64 + l;      // LDS granule 0..1023
    const int q = j >> 5;                    // code-in-tile 0..31
    const int g = (j & 31) ^ (q & 7);        // source granule (un-swizzle)
    srcOff[i] = q * 512 + g * 16;
  }
  // stage es tile 0 into buf 0 (buf1 aliases tileF: tile1 staged in main loop)
  #pragma unroll
  for (int i = 0; i < 4; ++i)
    load16(Eb + srcOff[i], esb + (i * 4 + w) * 1024);
  // eNorm -> LDS (wave-uniform dst + lane*16)
  load16((const char*)(ws + WS_ENORM) + t * 16, (char*)eNormS + w * 1024);

  // ---- prologue: z (c-major) -> zs (row-major bf16, swizzled) + |z|^2 ----
  const float* zb0 = z + (size_t)n * (CDIM * 1024) + hw0;
  const int cA = (t >> 4) * 2, hA = (t & 15) * 4;   // loader: 2 c-rows x 4 hw
  const int r2 = t >> 2, csub = t & 3;              // packer: row r2, 8-c group
  float4 v0 = *(const float4*)(zb0 + (size_t)cA * 1024 + hA);
  float4 v1 = *(const float4*)(zb0 + (size_t)(cA + 1) * 1024 + hA);
  float znAcc = 0.f;
  for (int ci = 0; ci < 8; ++ci) {
    __syncthreads();                         // tileF free
    *(float4*)(tileF + cA * 66 + hA)       = v0;
    *(float4*)(tileF + (cA + 1) * 66 + hA) = v1;
    if (ci < 7) {
      const float* src = zb0 + (size_t)((ci + 1) * 32 + cA) * 1024 + hA;
      v0 = *(const float4*)(src);
      v1 = *(const float4*)(src + 1024);
    }
    __syncthreads();                         // tileF ready
    union { bf16x8 v; unsigned short u[8]; } pk;
    #pragma unroll
    for (int k = 0; k < 8; ++k) {
      const float sv = tileF[(csub * 8 + k) * 66 + r2];
      znAcc += sv * sv;
      pk.u[k] = f2bf(sv);
    }
    const int g  = ci * 4 + csub;            // logical granule 0..31
    const int gp = g ^ (r2 & 7);
    *(bf16x8*)((char*)zs + r2 * 512 + gp * 16) = pk.v;
  }
  znPart[t] = znAcc;
  __syncthreads();                           // zs + eNorm + tile 0 ready; tileF dead

  // ---- cache A fragments: per wave 32 rows x K=256 in registers ----
  const int rhalf = w & 1, chalf = w >> 1;   // rows half, code half-of-tile
  const int lrow = l & 15, lk = l >> 4;
  bf16x8 af[2][8];
  #pragma unroll
  for (int rs = 0; rs < 2; ++rs) {
    const int r = rhalf * 32 + rs * 16 + lrow;
    #pragma unroll
    for (int kg = 0; kg < 8; ++kg) {
      const int gp = (kg * 4 + lk) ^ (r & 7);
      af[rs][kg] = *(const bf16x8*)((const char*)zs + r * 512 + gp * 16);
    }
  }

  // ---- main loop: 32 tiles x 32 codes, double-buffered es ----
  float bb[2][4]; int bidx[2][4];
  #pragma unroll
  for (int rs = 0; rs < 2; ++rs)
    #pragma unroll
    for (int i = 0; i < 4; ++i) { bb[rs][i] = 3.4e38f; bidx[rs][i] = 0; }

  const int q = chalf * 16 + lrow;           // code-in-tile for this lane
  for (int tile = 0; tile < 32; ++tile) {
    const int cur = tile & 1;
    if (tile < 31) {                         // stage next tile into other buf
      const char* src = Eb + (size_t)(tile + 1) * 16384;
      char* dst = esb + (cur ^ 1) * 16384;
      #pragma unroll
      for (int i = 0; i < 4; ++i)
        load16(src + srcOff[i], dst + (i * 4 + w) * 1024);
    }
    f32x4 acc[2];
    acc[0] = (f32x4){0.f, 0.f, 0.f, 0.f};
    acc[1] = (f32x4){0.f, 0.f, 0.f, 0.f};
    const char* ebase = (const char*)esb + cur * 16384 + q * 512;
    #pragma unroll
    for (int kg = 0; kg < 8; ++kg) {
      const int gp = (kg * 4 + lk) ^ (q & 7);
      const bf16x8 bf = *(const bf16x8*)(ebase + gp * 16);
      acc[0] = __builtin_amdgcn_mfma_f32_16x16x32_bf16(af[0][kg], bf, acc[0], 0, 0, 0);
      acc[1] = __builtin_amdgcn_mfma_f32_16x16x32_bf16(af[1][kg], bf, acc[1], 0, 0, 0);
    }
    // fold scores (codes ascending over tiles; strict < keeps first index)
    const int code = tile * 32 + q;
    const float eN = eNormS[code];
    #pragma unroll
    for (int rs = 0; rs < 2; ++rs)
      #pragma unroll
      for (int i = 0; i < 4; ++i) {
        const float sc = fmaf(-2.f, acc[rs][i], eN);
        if (sc < bb[rs][i]) { bb[rs][i] = sc; bidx[rs][i] = code; }
      }
    __syncthreads();                         // es[cur] consumed; staging drained
  }

  // ---- reduce over 16 code-lanes, cross-wave combine, loss ----
  #pragma unroll
  for (int rs = 0; rs < 2; ++rs)
    #pragma unroll
    for (int i = 0; i < 4; ++i)
      #pragma unroll
      for (int m = 8; m >= 1; m >>= 1) {
        const float ob = __shfl_xor(bb[rs][i], m);
        const int   oi = __shfl_xor(bidx[rs][i], m);
        if (ob < bb[rs][i] || (ob == bb[rs][i] && oi < bidx[rs][i])) { bb[rs][i] = ob; bidx[rs][i] = oi; }
      }
  if (lrow == 0) {
    #pragma unroll
    for (int rs = 0; rs < 2; ++rs)
      #pragma unroll
      for (int i = 0; i < 4; ++i) {
        float2 c2; c2.x = bb[rs][i]; c2.y = __int_as_float(bidx[rs][i]);
        cand[chalf * 64 + rhalf * 32 + rs * 16 + lk * 4 + i] = c2;
      }
  }
  __syncthreads();
  if (t < 64) {
    const float2 ca = cand[t], cb = cand[64 + t];
    float best = ca.x; int bi = __float_as_int(ca.y);
    const int b2 = __float_as_int(cb.y);
    if (cb.x < best || (cb.x == best && b2 < bi)) { best = cb.x; bi = b2; }
    idxS[t] = bi;
    float d = znPart[t * 4] + znPart[t * 4 + 1] + znPart[t * 4 + 2] + znPart[t * 4 + 3] + best;
    #pragma unroll
    for (int m = 32; m >= 1; m >>= 1) d += __shfl_xor(d, m);
    if (t == 0) atomicAdd((float*)(ws + WS_LOSS), d);
  }
  __syncthreads();                           // idxS ready; zs/es dead

  // ---- fused gather: quant_z = E[idx] (f32 exact), 2 c-passes of 128 ----
  const int rIdx = t >> 2, qg = t & 3;
  const int gidx = idxS[rIdx];
  const float* erow = E + (size_t)gidx * CDIM;
  float* obase = out + (size_t)n * (CDIM * 1024) + hw0;
  const int ci2 = t >> 4, hwq = t & 15;
  #pragma unroll
  for (int p = 0; p < 2; ++p) {
    #pragma unroll
    for (int j = 0; j < 8; ++j) {
      const int cc = qg + j * 4;             // 0..31
      const float4 v = *(const float4*)(erow + p * 128 + cc * 4);
      gtile[(cc * 4 + 0) * GT_STRIDE + rIdx] = v.x;
      gtile[(cc * 4 + 1) * GT_STRIDE + rIdx] = v.y;
      gtile[(cc * 4 + 2) * GT_STRIDE + rIdx] = v.z;
      gtile[(cc * 4 + 3) * GT_STRIDE + rIdx] = v.w;
    }
    __syncthreads();
    #pragma unroll
    for (int j = 0; j < 8; ++j) {
      const int cl = ci2 + j * 16;           // 0..127
      float4 v;
      v.x = gtile[cl * GT_STRIDE + hwq * 4 + 0];
      v.y = gtile[cl * GT_STRIDE + hwq * 4 + 1];
      v.z = gtile[cl * GT_STRIDE + hwq * 4 + 2];
      v.w = gtile[cl * GT_STRIDE + hwq * 4 + 3];
      *(float4*)(obase + (size_t)(p * 128 + cl) * 1024 + hwq * 4) = v;
    }
    if (p == 0) __syncthreads();             // gtile reads done before pass-1 writes
  }

  // ---- last-block loss finalize ----
  if (t == 0) {
    __threadfence();
    const unsigned done = atomicAdd((unsigned*)(ws + WS_CNT), 1u);
    if (done == 511u) {
      const float L = atomicAdd((float*)(ws + WS_LOSS), 0.0f) * (1.0f / 8388608.0f);
      out[8388608] = L;
      out[8388609] = 0.25f * L;
    }
  }
}

extern "C" void kernel_launch(void* const* d_in, const int* in_sizes, int n_in,
                              void* d_out, int out_size, void* d_ws, size_t ws_size,
                              hipStream_t stream) {
  const float* z = (const float*)d_in[0];
  const float* E = (const float*)d_in[1];
  float* out = (float*)d_out;
  char*  ws  = (char*)d_ws;

  static const int kLds = LDS_TOTAL;
  (void)hipFuncSetAttribute((const void*)vq_main,
                            hipFuncAttributeMaxDynamicSharedMemorySize, kLds);

  vq_prep_e <<<256, 256, 0, stream>>>(E, ws);
  vq_main   <<<512, 256, kLds, stream>>>(z, E, ws, out);
}

// Round 5
// 131.688 us; speedup vs baseline: 1.0002x; 1.0002x over previous
//
#include <hip/hip_runtime.h>
#include <stdint.h>

// VQ-VAE vector quantizer, MI355X — 3 blocks/CU (zs eliminated, af built direct).
// z: (32, 256, 32, 32) fp32 ; embedding: (1024, 256) fp32
// out: [0, 8388608) quant_z (N,C,H,W) ; [8388608] vq_loss ; [8388609] commit_loss
//
//   argmin_k ||z-e_k||^2 = argmin_k ( ||e_k||^2 - 2 z.e_k )   [bf16 MFMA scores]
//   vq_loss = (sum_m (||z_m||^2 + s_min(m))) / (M*C), commit = 0.25*vq_loss
//
// Round-5: 512 blocks x 256 thr (4 waves), 64 z-rows/block. The zs LDS buffer
// (32 KB) is deleted: its only consumer was the af register fragments, which are
// now packed directly from the tileF transpose tile during each prologue chunk
// (chunk ci == kg; reads are 32-bank/2-lane conflict-free). LDS = 46.5 KB ->
// THREE independent blocks/CU: prologue (HBM latency) / main loop (LDS+MFMA) /
// gather (HBM) phases of co-resident blocks overlap.

#define CDIM  256

// ws byte offsets
#define WS_EB     16777216u    // bf16[1024][256] row-major (512 KB)
#define WS_ENORM  17301504u    // f32[1024]
#define WS_CNT    17436672u    // u32 completion counter
#define WS_LOSS   19664896u    // f32

// LDS byte offsets (dynamic shared, 47616 total -> 3 blocks/CU)
#define L_ES     0u            // bf16 [2][32 codes][256 c], swizzled, double buffer
#define L_TILEF  32768u        // f32[32][66] transpose scratch (8448)
#define L_ENORM  41216u        // f32[1024]
#define L_ZNP    45312u        // f32[64][4]
#define L_CAND   46336u        // float2[128]
#define L_IDX    47360u        // i32[64]
#define LDS_TOTAL 47616
#define GT_STRIDE 67           // gather tile f32[128 c][67] aliased at 0 (34304 B)

typedef __attribute__((ext_vector_type(8))) short bf16x8;
typedef __attribute__((ext_vector_type(4))) float f32x4;

__device__ inline unsigned short f2bf(float f) {
  uint32_t u = __float_as_uint(f);
  return (unsigned short)((u + 0x7FFFu + ((u >> 16) & 1u)) >> 16);
}

__device__ inline void load16(const void* g, void* l) {
  __builtin_amdgcn_global_load_lds((const __attribute__((address_space(1))) void*)g,
                                   (__attribute__((address_space(3))) void*)l, 16, 0, 0);
}

// E -> bf16 Eb (row-major) + eNorm ; zero loss + counter. 256 blocks x 256 thr.
__global__ void vq_prep_e(const float* __restrict__ E, char* __restrict__ ws) {
  const int w = threadIdx.x >> 6, l = threadIdx.x & 63;
  const int row = blockIdx.x * 4 + w;
  const float4 v = *(const float4*)(E + (size_t)row * CDIM + l * 4);
  ushort4 b;
  b.x = f2bf(v.x); b.y = f2bf(v.y); b.z = f2bf(v.z); b.w = f2bf(v.w);
  *(ushort4*)(ws + WS_EB + (size_t)row * 512 + l * 8) = b;
  float s = v.x * v.x + v.y * v.y + v.z * v.z + v.w * v.w;
  #pragma unroll
  for (int m = 32; m >= 1; m >>= 1) s += __shfl_xor(s, m);
  if (l == 0) ((float*)(ws + WS_ENORM))[row] = s;
  if (blockIdx.x == 0 && threadIdx.x == 0) {
    *((float*)(ws + WS_LOSS)) = 0.f;
    *((unsigned*)(ws + WS_CNT)) = 0u;
  }
}

// 512 blocks x 256 thr: 64 z-rows resident in registers; 1024 codes streamed
// through LDS; argmin + loss + fused quant_z gather + last-block loss finalize.
__global__ __launch_bounds__(256, 3)
void vq_main(const float* __restrict__ z, const float* __restrict__ E,
             char* __restrict__ ws, float* __restrict__ out) {
  extern __shared__ char lds[];
  char* esb          = lds + L_ES;
  float* tileF       = (float*)(lds + L_TILEF);
  float* eNormS      = (float*)(lds + L_ENORM);
  float* znPart      = (float*)(lds + L_ZNP);
  float2* cand       = (float2*)(lds + L_CAND);
  int* idxS          = (int*)(lds + L_IDX);
  float* gtile       = (float*)(lds);          // epilogue, aliases es+tileF (dead)

  const int t = threadIdx.x, w = t >> 6, l = t & 63;
  const int mt = blockIdx.x;                   // 0..511
  const int n = mt >> 4, hw0 = (mt & 15) << 6;
  const char* Eb = ws + WS_EB;

  const int rhalf = w & 1, chalf = w >> 1;     // rows half, code half-of-tile
  const int lrow = l & 15, lk = l >> 4;

  // per-thread staging source offsets for one 32-code es tile (swizzle baked in)
  int srcOff[4];
  #pragma unroll
  for (int i = 0; i < 4; ++i) {
    const int j = (i * 4 + w) * 64 + l;      // LDS granule 0..1023
    const int q = j >> 5;                    // code-in-tile 0..31
    const int g = (j & 31) ^ (q & 7);        // source granule (un-swizzle)
    srcOff[i] = q * 512 + g * 16;
  }
  // stage es tile 0 into buf 0 ; eNorm -> LDS (wave-uniform dst + lane*16)
  #pragma unroll
  for (int i = 0; i < 4; ++i)
    load16(Eb + srcOff[i], esb + (i * 4 + w) * 1024);
  load16((const char*)(ws + WS_ENORM) + t * 16, (char*)eNormS + w * 1024);

  // ---- prologue: z (c-major) -> tileF -> af register fragments + |z|^2 ----
  // chunk ci covers c in [ci*32, ci*32+32) == MFMA k-group kg = ci.
  // af[rs][kg] = bf16x8 of z[row r][c = kg*32 + lk*8 + 0..7], r = rhalf*32+rs*16+lrow.
  const float* zb0 = z + (size_t)n * (CDIM * 1024) + hw0;
  const int cA = (t >> 4) * 2, hA = (t & 15) * 4;   // loader: 2 c-rows x 4 hw
  float4 v0 = *(const float4*)(zb0 + (size_t)cA * 1024 + hA);
  float4 v1 = *(const float4*)(zb0 + (size_t)(cA + 1) * 1024 + hA);
  bf16x8 af[2][8];
  float znAcc[2] = {0.f, 0.f};
  for (int ci = 0; ci < 8; ++ci) {
    __syncthreads();                         // tileF free (prev af reads done)
    *(float4*)(tileF + cA * 66 + hA)       = v0;
    *(float4*)(tileF + (cA + 1) * 66 + hA) = v1;
    if (ci < 7) {
      const float* src = zb0 + (size_t)((ci + 1) * 32 + cA) * 1024 + hA;
      v0 = *(const float4*)(src);
      v1 = *(const float4*)(src + 1024);
    }
    __syncthreads();                         // tileF ready
    #pragma unroll
    for (int rs = 0; rs < 2; ++rs) {
      const int r = rhalf * 32 + rs * 16 + lrow;
      union { bf16x8 v; unsigned short u[8]; } pk;
      float sacc = 0.f;
      #pragma unroll
      for (int k = 0; k < 8; ++k) {
        const float sv = tileF[(lk * 8 + k) * 66 + r];
        sacc += sv * sv;
        pk.u[k] = f2bf(sv);
      }
      af[rs][ci] = pk.v;
      znAcc[rs] += sacc;
    }
  }
  if (chalf == 0) {                          // one code-half owns the norms
    #pragma unroll
    for (int rs = 0; rs < 2; ++rs)
      znPart[(rhalf * 32 + rs * 16 + lrow) * 4 + lk] = znAcc[rs];
  }
  __syncthreads();                           // znPart + eNorm + tile 0 ready

  // ---- main loop: 32 tiles x 32 codes, double-buffered es ----
  float bb[2][4]; int bidx[2][4];
  #pragma unroll
  for (int rs = 0; rs < 2; ++rs)
    #pragma unroll
    for (int i = 0; i < 4; ++i) { bb[rs][i] = 3.4e38f; bidx[rs][i] = 0; }

  const int q = chalf * 16 + lrow;           // code-in-tile for this lane
  for (int tile = 0; tile < 32; ++tile) {
    const int cur = tile & 1;
    if (tile < 31) {                         // stage next tile into other buf
      const char* src = Eb + (size_t)(tile + 1) * 16384;
      char* dst = esb + (cur ^ 1) * 16384;
      #pragma unroll
      for (int i = 0; i < 4; ++i)
        load16(src + srcOff[i], dst + (i * 4 + w) * 1024);
    }
    f32x4 acc[2];
    acc[0] = (f32x4){0.f, 0.f, 0.f, 0.f};
    acc[1] = (f32x4){0.f, 0.f, 0.f, 0.f};
    const char* ebase = (const char*)esb + cur * 16384 + q * 512;
    #pragma unroll
    for (int kg = 0; kg < 8; ++kg) {
      const int gp = (kg * 4 + lk) ^ (q & 7);
      const bf16x8 bf = *(const bf16x8*)(ebase + gp * 16);
      acc[0] = __builtin_amdgcn_mfma_f32_16x16x32_bf16(af[0][kg], bf, acc[0], 0, 0, 0);
      acc[1] = __builtin_amdgcn_mfma_f32_16x16x32_bf16(af[1][kg], bf, acc[1], 0, 0, 0);
    }
    // fold scores (codes ascending over tiles; strict < keeps first index)
    const int code = tile * 32 + q;
    const float eN = eNormS[code];
    #pragma unroll
    for (int rs = 0; rs < 2; ++rs)
      #pragma unroll
      for (int i = 0; i < 4; ++i) {
        const float sc = fmaf(-2.f, acc[rs][i], eN);
        if (sc < bb[rs][i]) { bb[rs][i] = sc; bidx[rs][i] = code; }
      }
    __syncthreads();                         // es[cur] consumed; staging drained
  }

  // ---- reduce over 16 code-lanes, cross-wave combine, loss ----
  #pragma unroll
  for (int rs = 0; rs < 2; ++rs)
    #pragma unroll
    for (int i = 0; i < 4; ++i)
      #pragma unroll
      for (int m = 8; m >= 1; m >>= 1) {
        const float ob = __shfl_xor(bb[rs][i], m);
        const int   oi = __shfl_xor(bidx[rs][i], m);
        if (ob < bb[rs][i] || (ob == bb[rs][i] && oi < bidx[rs][i])) { bb[rs][i] = ob; bidx[rs][i] = oi; }
      }
  if (lrow == 0) {
    #pragma unroll
    for (int rs = 0; rs < 2; ++rs)
      #pragma unroll
      for (int i = 0; i < 4; ++i) {
        float2 c2; c2.x = bb[rs][i]; c2.y = __int_as_float(bidx[rs][i]);
        cand[chalf * 64 + rhalf * 32 + rs * 16 + lk * 4 + i] = c2;
      }
  }
  __syncthreads();
  if (t < 64) {
    const float2 ca = cand[t], cb = cand[64 + t];
    float best = ca.x; int bi = __float_as_int(ca.y);
    const int b2 = __float_as_int(cb.y);
    if (cb.x < best || (cb.x == best && b2 < bi)) { best = cb.x; bi = b2; }
    idxS[t] = bi;
    float d = znPart[t * 4] + znPart[t * 4 + 1] + znPart[t * 4 + 2] + znPart[t * 4 + 3] + best;
    #pragma unroll
    for (int m = 32; m >= 1; m >>= 1) d += __shfl_xor(d, m);
    if (t == 0) atomicAdd((float*)(ws + WS_LOSS), d);
  }
  __syncthreads();                           // idxS ready; es/tileF dead

  // ---- fused gather: quant_z = E[idx] (f32 exact), 2 c-passes of 128 ----
  const int rIdx = t >> 2, qg = t & 3;
  const int gidx = idxS[rIdx];
  const float* erow = E + (size_t)gidx * CDIM;
  float* obase = out + (size_t)n * (CDIM * 1024) + hw0;
  const int ci2 = t >> 4, hwq = t & 15;
  #pragma unroll
  for (int p = 0; p < 2; ++p) {
    #pragma unroll
    for (int j = 0; j < 8; ++j) {
      const int cc = qg + j * 4;             // 0..31
      const float4 v = *(const float4*)(erow + p * 128 + cc * 4);
      gtile[(cc * 4 + 0) * GT_STRIDE + rIdx] = v.x;
      gtile[(cc * 4 + 1) * GT_STRIDE + rIdx] = v.y;
      gtile[(cc * 4 + 2) * GT_STRIDE + rIdx] = v.z;
      gtile[(cc * 4 + 3) * GT_STRIDE + rIdx] = v.w;
    }
    __syncthreads();
    #pragma unroll
    for (int j = 0; j < 8; ++j) {
      const int cl = ci2 + j * 16;           // 0..127
      float4 v;
      v.x = gtile[cl * GT_STRIDE + hwq * 4 + 0];
      v.y = gtile[cl * GT_STRIDE + hwq * 4 + 1];
      v.z = gtile[cl * GT_STRIDE + hwq * 4 + 2];
      v.w = gtile[cl * GT_STRIDE + hwq * 4 + 3];
      *(float4*)(obase + (size_t)(p * 128 + cl) * 1024 + hwq * 4) = v;
    }
    if (p == 0) __syncthreads();             // gtile reads done before pass-1 writes
  }

  // ---- last-block loss finalize ----
  if (t == 0) {
    __threadfence();
    const unsigned done = atomicAdd((unsigned*)(ws + WS_CNT), 1u);
    if (done == 511u) {
      const float L = atomicAdd((float*)(ws + WS_LOSS), 0.0f) * (1.0f / 8388608.0f);
      out[8388608] = L;
      out[8388609] = 0.25f * L;
    }
  }
}

extern "C" void kernel_launch(void* const* d_in, const int* in_sizes, int n_in,
                              void* d_out, int out_size, void* d_ws, size_t ws_size,
                              hipStream_t stream) {
  const float* z = (const float*)d_in[0];
  const float* E = (const float*)d_in[1];
  float* out = (float*)d_out;
  char*  ws  = (char*)d_ws;

  static const int kLds = LDS_TOTAL;
  (void)hipFuncSetAttribute((const void*)vq_main,
                            hipFuncAttributeMaxDynamicSharedMemorySize, kLds);

  vq_prep_e <<<256, 256, 0, stream>>>(E, ws);
  vq_main   <<<512, 256, kLds, stream>>>(z, E, ws, out);
}

// Round 6
// 124.662 us; speedup vs baseline: 1.0566x; 1.0564x over previous
//
#include <hip/hip_runtime.h>
#include <stdint.h>

// VQ-VAE vector quantizer, MI355X — phase-split pipeline (measure + decouple).
// z: (32, 256, 32, 32) fp32 ; embedding: (1024, 256) fp32
// out: [0, 8388608) quant_z (N,C,H,W) ; [8388608] vq_loss ; [8388609] commit_loss
//
//   argmin_k ||z-e_k||^2 = argmin_k ( ||e_k||^2 - 2 z.e_k )   [bf16 MFMA scores]
//   vq_loss = (sum_m (||z_m||^2 + s_min(m))) / (M*C), commit = 0.25*vq_loss
//
// Round-6: 4 kernels so each phase runs at its own occupancy and rocprof times
// them separately. vq_argmin dedups LDS reads: all 4 waves hold the SAME 64 rows
// in registers (af loaded from fragment-major zb16 in ws) and own DISTINCT
// code-quarters -> each staged E byte is ds_read exactly once (was 2x).

#define CDIM  256

// ws byte offsets
#define WS_ZB16   0u           // bf16 z-fragments, unit16B = (rb*8+kg)*64+lk*16+lrow (16 MB)
#define WS_EB     16777216u    // bf16[1024][256] row-major (512 KB)
#define WS_ENORM  17301504u    // f32[1024]
#define WS_ZNORM  17305600u    // f32[32768]
#define WS_IDX    17436672u    // i32[32768]
#define WS_LOSS   19664896u    // f32

typedef __attribute__((ext_vector_type(8))) short bf16x8;
typedef __attribute__((ext_vector_type(4))) float f32x4;

__device__ inline unsigned short f2bf(float f) {
  uint32_t u = __float_as_uint(f);
  return (unsigned short)((u + 0x7FFFu + ((u >> 16) & 1u)) >> 16);
}

__device__ inline void load16(const void* g, void* l) {
  __builtin_amdgcn_global_load_lds((const __attribute__((address_space(1))) void*)g,
                                   (__attribute__((address_space(3))) void*)l, 16, 0, 0);
}

// E -> bf16 Eb (row-major) + eNorm ; zero loss. 256 blocks x 256 thr.
__global__ void vq_prep_e(const float* __restrict__ E, char* __restrict__ ws) {
  const int w = threadIdx.x >> 6, l = threadIdx.x & 63;
  const int row = blockIdx.x * 4 + w;
  const float4 v = *(const float4*)(E + (size_t)row * CDIM + l * 4);
  ushort4 b;
  b.x = f2bf(v.x); b.y = f2bf(v.y); b.z = f2bf(v.z); b.w = f2bf(v.w);
  *(ushort4*)(ws + WS_EB + (size_t)row * 512 + l * 8) = b;
  float s = v.x * v.x + v.y * v.y + v.z * v.z + v.w * v.w;
  #pragma unroll
  for (int m = 32; m >= 1; m >>= 1) s += __shfl_xor(s, m);
  if (l == 0) ((float*)(ws + WS_ENORM))[row] = s;
  if (blockIdx.x == 0 && threadIdx.x == 0) *((float*)(ws + WS_LOSS)) = 0.f;
}

// z (c-major f32) -> zb16 (bf16 MFMA-fragment layout) + znorm. 512 blocks x 256.
// Fragment unit (16 B) for (row r, kg, lk) at unit = (rb*8+kg)*64 + lk*16 + lrow
// (rb = r>>4, lrow = r&15), holding z[r][kg*32+lk*8 .. +8] as bf16x8.
__global__ __launch_bounds__(256)
void vq_pack_z(const float* __restrict__ z, char* __restrict__ ws) {
  __shared__ float tileF[32 * 66];
  __shared__ float znPart[256];
  const int t = threadIdx.x;
  const int mt = blockIdx.x;                 // 0..511
  const int n = mt >> 4, hw0 = (mt & 15) << 6;
  const int m0 = mt << 6;
  const float* zb0 = z + (size_t)n * (CDIM * 1024) + hw0;
  const int cA = (t >> 4) * 2, hA = (t & 15) * 4;   // loader: 2 c-rows x 4 hw
  const int r = t >> 2, lk = t & 3;                 // packer: row r, c-subgroup lk
  const int rb = (m0 + r) >> 4, lrow = r & 15;
  char* zb16 = ws + WS_ZB16;

  float4 v0 = *(const float4*)(zb0 + (size_t)cA * 1024 + hA);
  float4 v1 = *(const float4*)(zb0 + (size_t)(cA + 1) * 1024 + hA);
  float znAcc = 0.f;
  for (int ci = 0; ci < 8; ++ci) {           // chunk ci == MFMA k-group kg
    __syncthreads();                         // tileF free
    *(float4*)(tileF + cA * 66 + hA)       = v0;
    *(float4*)(tileF + (cA + 1) * 66 + hA) = v1;
    if (ci < 7) {
      const float* src = zb0 + (size_t)((ci + 1) * 32 + cA) * 1024 + hA;
      v0 = *(const float4*)(src);
      v1 = *(const float4*)(src + 1024);
    }
    __syncthreads();                         // tileF ready
    union { bf16x8 v; unsigned short u[8]; } pk;
    #pragma unroll
    for (int k = 0; k < 8; ++k) {            // c = ci*32 + lk*8 + k
      const float sv = tileF[(lk * 8 + k) * 66 + r];
      znAcc += sv * sv;
      pk.u[k] = f2bf(sv);
    }
    *(bf16x8*)(zb16 + ((size_t)((rb * 8 + ci) * 64 + lk * 16 + lrow)) * 16) = pk.v;
  }
  znPart[t] = znAcc;                         // (r,lk) -> r*4+lk == t
  __syncthreads();
  if (t < 64)
    ((float*)(ws + WS_ZNORM))[m0 + t] =
        znPart[t * 4] + znPart[t * 4 + 1] + znPart[t * 4 + 2] + znPart[t * 4 + 3];
}

// Argmin: 512 blocks x 256 thr (4 waves). All waves hold the SAME 64 rows in
// registers (af from zb16); waves own distinct 16-code columns of each 64-code
// tile -> every staged E byte is ds_read exactly once. es double-buffered.
__global__ __launch_bounds__(256, 2)
void vq_argmin(char* __restrict__ ws) {
  extern __shared__ char lds[];
  char* esb     = lds;                       // bf16 [2][64 codes][256 c] swizzled
  float* eNormS = (float*)(lds + 65536);     // f32[1024]
  float2* cand  = (float2*)(lds + 69632);    // [4 waves][64 rows]

  const int t = threadIdx.x, w = t >> 6, l = t & 63;
  const int mt = blockIdx.x;                 // 0..511
  const int m0 = mt << 6;
  const char* Eb   = ws + WS_EB;
  const char* zb16 = ws + WS_ZB16;
  const int lrow = l & 15, lk = l >> 4;

  // staging source offsets for one 64-code tile (XOR granule swizzle baked in)
  int srcOff[8];
  #pragma unroll
  for (int i = 0; i < 8; ++i) {
    const int j = (i * 4 + w) * 64 + l;      // LDS granule 0..2047
    const int q = j >> 5;                    // code-in-tile 0..63
    const int g = (j & 31) ^ (q & 7);        // source granule (un-swizzle)
    srcOff[i] = q * 512 + g * 16;
  }
  #pragma unroll
  for (int i = 0; i < 8; ++i)                // stage tile 0 into buf 0
    load16(Eb + srcOff[i], esb + (i * 4 + w) * 1024);
  load16((const char*)(ws + WS_ENORM) + t * 16, (char*)eNormS + w * 1024);

  // af: 64 rows x K=256, identical in all 4 waves (unit-stride lane loads)
  bf16x8 af[4][8];
  const int rb0 = mt * 4;
  #pragma unroll
  for (int rs = 0; rs < 4; ++rs)
    #pragma unroll
    for (int kg = 0; kg < 8; ++kg)
      af[rs][kg] = *(const bf16x8*)(zb16 + ((size_t)(((rb0 + rs) * 8 + kg) * 64 + l)) * 16);
  __syncthreads();                           // tile 0 + eNorm staged

  float bb[4][4]; int bidx[4][4];
  #pragma unroll
  for (int rs = 0; rs < 4; ++rs)
    #pragma unroll
    for (int i = 0; i < 4; ++i) { bb[rs][i] = 3.4e38f; bidx[rs][i] = 0; }

  const int q = w * 16 + lrow;               // code-in-tile for this lane (per wave)
  for (int tile = 0; tile < 16; ++tile) {
    const int cur = tile & 1;
    if (tile < 15) {                         // stage next tile into other buf
      const char* src = Eb + (size_t)(tile + 1) * 32768;
      char* dst = esb + (cur ^ 1) * 32768;
      #pragma unroll
      for (int i = 0; i < 8; ++i)
        load16(src + srcOff[i], dst + (i * 4 + w) * 1024);
    }
    f32x4 acc[4];
    #pragma unroll
    for (int rs = 0; rs < 4; ++rs) acc[rs] = (f32x4){0.f, 0.f, 0.f, 0.f};
    const char* ebase = (const char*)esb + cur * 32768 + q * 512;
    #pragma unroll
    for (int kg = 0; kg < 8; ++kg) {
      const int gp = (kg * 4 + lk) ^ (q & 7);
      const bf16x8 bf = *(const bf16x8*)(ebase + gp * 16);
      #pragma unroll
      for (int rs = 0; rs < 4; ++rs)
        acc[rs] = __builtin_amdgcn_mfma_f32_16x16x32_bf16(af[rs][kg], bf, acc[rs], 0, 0, 0);
    }
    const int code = tile * 64 + q;
    const float eN = eNormS[code];
    #pragma unroll
    for (int rs = 0; rs < 4; ++rs)
      #pragma unroll
      for (int i = 0; i < 4; ++i) {
        const float sc = fmaf(-2.f, acc[rs][i], eN);
        if (sc < bb[rs][i]) { bb[rs][i] = sc; bidx[rs][i] = code; }
      }
    __syncthreads();                         // es[cur] consumed; staging drained
  }

  // reduce over 16 code-lanes (lrow bits), then cross-wave via LDS
  #pragma unroll
  for (int rs = 0; rs < 4; ++rs)
    #pragma unroll
    for (int i = 0; i < 4; ++i)
      #pragma unroll
      for (int m = 8; m >= 1; m >>= 1) {
        const float ob = __shfl_xor(bb[rs][i], m);
        const int   oi = __shfl_xor(bidx[rs][i], m);
        if (ob < bb[rs][i] || (ob == bb[rs][i] && oi < bidx[rs][i])) { bb[rs][i] = ob; bidx[rs][i] = oi; }
      }
  if (lrow == 0) {
    #pragma unroll
    for (int rs = 0; rs < 4; ++rs)
      #pragma unroll
      for (int i = 0; i < 4; ++i) {
        float2 c2; c2.x = bb[rs][i]; c2.y = __int_as_float(bidx[rs][i]);
        cand[w * 64 + rs * 16 + lk * 4 + i] = c2;   // row = rs*16+lk*4+i
      }
  }
  __syncthreads();
  if (t < 64) {
    float best = 3.4e38f; int bi = 0x7fffffff;
    #pragma unroll
    for (int wv = 0; wv < 4; ++wv) {
      const float2 c2 = cand[wv * 64 + t];
      const int ci2 = __float_as_int(c2.y);
      if (c2.x < best || (c2.x == best && ci2 < bi)) { best = c2.x; bi = ci2; }
    }
    ((int*)(ws + WS_IDX))[m0 + t] = bi;
    float d = ((const float*)(ws + WS_ZNORM))[m0 + t] + best;
    #pragma unroll
    for (int m = 32; m >= 1; m >>= 1) d += __shfl_xor(d, m);
    if (t == 0) atomicAdd((float*)(ws + WS_LOSS), d);
  }
}

// Gather quant_z (f32 exact) via padded LDS transpose; block 0 writes losses.
__global__ __launch_bounds__(256, 4)
void vq_gather(const float* __restrict__ E, const char* __restrict__ ws,
               float* __restrict__ out) {
  __shared__ float tile[256][33];
  __shared__ int idxS[32];
  const int t = threadIdx.x;
  const int n = blockIdx.x >> 5, hw0 = (blockIdx.x & 31) * 32;
  if (t < 32) idxS[t] = ((const int*)(ws + WS_IDX))[n * 1024 + hw0 + t];
  if (blockIdx.x == 0 && t == 0) {           // argmin kernel already complete
    const float L = *((const float*)(ws + WS_LOSS)) * (1.0f / 8388608.0f);
    out[8388608] = L;
    out[8388609] = 0.25f * L;
  }
  __syncthreads();

  const int hw = t >> 3, q = t & 7;
  const float4* erow = (const float4*)(E + (size_t)idxS[hw] * CDIM);
  #pragma unroll
  for (int j = 0; j < 8; ++j) {
    const int p = q + j * 8;
    const float4 v = erow[p];
    tile[p * 4 + 0][hw] = v.x;
    tile[p * 4 + 1][hw] = v.y;
    tile[p * 4 + 2][hw] = v.z;
    tile[p * 4 + 3][hw] = v.w;
  }
  __syncthreads();

  float* obase = out + (size_t)n * (CDIM * 1024) + hw0;
  const int hw4 = (t & 7) * 4, c0 = t >> 3;
  #pragma unroll
  for (int j = 0; j < 8; ++j) {
    const int c = c0 + j * 32;
    float4 v;
    v.x = tile[c][hw4 + 0];
    v.y = tile[c][hw4 + 1];
    v.z = tile[c][hw4 + 2];
    v.w = tile[c][hw4 + 3];
    *(float4*)(obase + (size_t)c * 1024 + hw4) = v;
  }
}

extern "C" void kernel_launch(void* const* d_in, const int* in_sizes, int n_in,
                              void* d_out, int out_size, void* d_ws, size_t ws_size,
                              hipStream_t stream) {
  const float* z = (const float*)d_in[0];
  const float* E = (const float*)d_in[1];
  float* out = (float*)d_out;
  char*  ws  = (char*)d_ws;

  static const int kLdsArg = 71680;          // es 64K + eNorm 4K + cand 2K
  (void)hipFuncSetAttribute((const void*)vq_argmin,
                            hipFuncAttributeMaxDynamicSharedMemorySize, kLdsArg);

  vq_prep_e <<<256, 256, 0, stream>>>(E, ws);
  vq_pack_z <<<512, 256, 0, stream>>>(z, ws);
  vq_argmin <<<512, 256, kLdsArg, stream>>>(ws);
  vq_gather <<<1024, 256, 0, stream>>>(E, ws, out);
}

// Round 7
// 122.251 us; speedup vs baseline: 1.0774x; 1.0197x over previous
//
#include <hip/hip_runtime.h>
#include <stdint.h>

// VQ-VAE vector quantizer, MI355X — barrier-free per-wave argmin pipeline.
// z: (32, 256, 32, 32) fp32 ; embedding: (1024, 256) fp32
// out: [0, 8388608) quant_z (N,C,H,W) ; [8388608] vq_loss ; [8388609] commit_loss
//
//   argmin_k ||z-e_k||^2 = argmin_k ( ||e_k||^2 - 2 z.e_k )   [bf16 MFMA scores]
//   vq_loss = (sum_m (||z_m||^2 + s_min(m))) / (M*C), commit = 0.25*vq_loss
//
// Round-7: 3 dispatches. vq_argmin gives each of the 4 waves a PRIVATE
// double-buffered LDS region and a private 256-code range: the main loop has
// ZERO s_barrier — per-wave counted s_waitcnt vmcnt(8) only (stage chunk t+1,
// wait for chunk t, never drain). pack_z and prep_e merged into one dispatch.

#define CDIM  256

// ws byte offsets
#define WS_ZB16   0u           // bf16 z-fragments, unit16B = (rb*8+kg)*64+lk*16+lrow (16 MB)
#define WS_EB     16777216u    // bf16[1024][256] row-major (512 KB)
#define WS_ENORM  17301504u    // f32[1024]
#define WS_ZNORM  17305600u    // f32[32768]
#define WS_IDX    17436672u    // i32[32768]
#define WS_LOSS   19664896u    // f32

typedef __attribute__((ext_vector_type(8))) short bf16x8;
typedef __attribute__((ext_vector_type(4))) float f32x4;

__device__ inline unsigned short f2bf(float f) {
  uint32_t u = __float_as_uint(f);
  return (unsigned short)((u + 0x7FFFu + ((u >> 16) & 1u)) >> 16);
}

__device__ inline void load16(const void* g, void* l) {
  __builtin_amdgcn_global_load_lds((const __attribute__((address_space(1))) void*)g,
                                   (__attribute__((address_space(3))) void*)l, 16, 0, 0);
}

// blocks 0..511: z (c-major f32) -> zb16 (bf16 MFMA-fragment layout) + znorm.
// blocks 512..767: E -> bf16 Eb (row-major) + eNorm ; block 512 zeroes loss.
__global__ __launch_bounds__(256)
void vq_pack(const float* __restrict__ z, const float* __restrict__ E,
             char* __restrict__ ws) {
  __shared__ float tileF[32 * 66];
  __shared__ float znPart[256];
  const int t = threadIdx.x;
  const int mt = blockIdx.x;

  if (mt >= 512) {                           // ---- prep_e part ----
    const int bb = mt - 512;                 // 0..255
    const int w = t >> 6, l = t & 63;
    const int row = bb * 4 + w;
    const float4 v = *(const float4*)(E + (size_t)row * CDIM + l * 4);
    ushort4 b;
    b.x = f2bf(v.x); b.y = f2bf(v.y); b.z = f2bf(v.z); b.w = f2bf(v.w);
    *(ushort4*)(ws + WS_EB + (size_t)row * 512 + l * 8) = b;
    float s = v.x * v.x + v.y * v.y + v.z * v.z + v.w * v.w;
    #pragma unroll
    for (int m = 32; m >= 1; m >>= 1) s += __shfl_xor(s, m);
    if (l == 0) ((float*)(ws + WS_ENORM))[row] = s;
    if (bb == 0 && t == 0) *((float*)(ws + WS_LOSS)) = 0.f;
    return;
  }

  // ---- pack_z part (proven round-6) ----
  const int n = mt >> 4, hw0 = (mt & 15) << 6;
  const int m0 = mt << 6;
  const float* zb0 = z + (size_t)n * (CDIM * 1024) + hw0;
  const int cA = (t >> 4) * 2, hA = (t & 15) * 4;   // loader: 2 c-rows x 4 hw
  const int r = t >> 2, lk = t & 3;                 // packer: row r, c-subgroup lk
  const int rb = (m0 + r) >> 4, lrow = r & 15;
  char* zb16 = ws + WS_ZB16;

  float4 v0 = *(const float4*)(zb0 + (size_t)cA * 1024 + hA);
  float4 v1 = *(const float4*)(zb0 + (size_t)(cA + 1) * 1024 + hA);
  float znAcc = 0.f;
  for (int ci = 0; ci < 8; ++ci) {           // chunk ci == MFMA k-group kg
    __syncthreads();                         // tileF free
    *(float4*)(tileF + cA * 66 + hA)       = v0;
    *(float4*)(tileF + (cA + 1) * 66 + hA) = v1;
    if (ci < 7) {
      const float* src = zb0 + (size_t)((ci + 1) * 32 + cA) * 1024 + hA;
      v0 = *(const float4*)(src);
      v1 = *(const float4*)(src + 1024);
    }
    __syncthreads();                         // tileF ready
    union { bf16x8 v; unsigned short u[8]; } pk;
    #pragma unroll
    for (int k = 0; k < 8; ++k) {            // c = ci*32 + lk*8 + k
      const float sv = tileF[(lk * 8 + k) * 66 + r];
      znAcc += sv * sv;
      pk.u[k] = f2bf(sv);
    }
    *(bf16x8*)(zb16 + ((size_t)((rb * 8 + ci) * 64 + lk * 16 + lrow)) * 16) = pk.v;
  }
  znPart[t] = znAcc;                         // (r,lk) -> r*4+lk == t
  __syncthreads();
  if (t < 64)
    ((float*)(ws + WS_ZNORM))[m0 + t] =
        znPart[t * 4] + znPart[t * 4 + 1] + znPart[t * 4 + 2] + znPart[t * 4 + 3];
}

// Argmin: 512 blocks x 256 thr (4 independent waves). Wave w owns codes
// [w*256, w*256+256) in 16 chunks of 16; private 2x8KB LDS double buffer;
// main loop has no s_barrier — per-wave counted vmcnt only.
__global__ __launch_bounds__(256, 2)
void vq_argmin(char* __restrict__ ws) {
  extern __shared__ char lds[];
  const int t = threadIdx.x, w = t >> 6, l = t & 63;
  const int lrow = l & 15, lk = l >> 4;
  const int mt = blockIdx.x;                 // 0..511
  const int m0 = mt << 6;
  const char* Eb   = ws + WS_EB;
  const char* zb16 = ws + WS_ZB16;

  char* bufA    = lds + w * 16384;           // wave-private chunk buffers
  char* bufB    = bufA + 8192;
  float* eNormW = (float*)(lds + 65536 + w * 1024);  // wave's 256 norms
  float2* cand  = (float2*)(lds + 69632);    // [4 waves][64 rows]

  // staging source offsets for one 16-code chunk (XOR granule swizzle baked in):
  // LDS[q][s] = E[q][s ^ (q&7)], q = code-in-chunk, s/granule of 16 B.
  int srcOff[8];
  #pragma unroll
  for (int i = 0; i < 8; ++i) {
    const int j = i * 64 + l;                // LDS granule 0..511
    const int q = j >> 5;                    // code-in-chunk 0..15
    const int g = (j & 31) ^ (q & 7);        // source granule (un-swizzle)
    srcOff[i] = q * 512 + g * 16;
  }
  const char* EbW = Eb + (size_t)w * 131072; // wave's 256 codes (128 KB)

  // stage chunk 0 + wave's eNorm slice (9 loads outstanding)
  #pragma unroll
  for (int i = 0; i < 8; ++i)
    load16(EbW + srcOff[i], bufA + i * 1024 + l * 16);
  load16((const char*)(ws + WS_ENORM) + w * 1024 + l * 16, (char*)eNormW + l * 16);

  // af: 64 rows x K=256, identical in all waves (proven round-6 layout)
  bf16x8 af[4][8];
  const int rb0 = mt * 4;
  #pragma unroll
  for (int rs = 0; rs < 4; ++rs)
    #pragma unroll
    for (int kg = 0; kg < 8; ++kg)
      af[rs][kg] = *(const bf16x8*)(zb16 + ((size_t)(((rb0 + rs) * 8 + kg) * 64 + l)) * 16);

  float bb[4][4]; int bidx[4][4];
  #pragma unroll
  for (int rs = 0; rs < 4; ++rs)
    #pragma unroll
    for (int i = 0; i < 4; ++i) { bb[rs][i] = 3.4e38f; bidx[rs][i] = 0; }

  char* bcur = bufA;
  char* bnxt = bufB;
  for (int ch = 0; ch < 16; ++ch) {
    if (ch < 15) {                           // stage next chunk into other buf
      const char* src = EbW + (size_t)(ch + 1) * 8192;
      #pragma unroll
      for (int i = 0; i < 8; ++i)
        load16(src + srcOff[i], bnxt + i * 1024 + l * 16);
      // retire everything except the 8 loads just issued (chunk ch ready)
      asm volatile("s_waitcnt vmcnt(8)" ::: "memory");
    } else {
      asm volatile("s_waitcnt vmcnt(0)" ::: "memory");
    }
    __builtin_amdgcn_sched_barrier(0);

    f32x4 acc[4];
    #pragma unroll
    for (int rs = 0; rs < 4; ++rs) acc[rs] = (f32x4){0.f, 0.f, 0.f, 0.f};
    const char* ebase = bcur + lrow * 512;
    #pragma unroll
    for (int kg = 0; kg < 8; ++kg) {
      const bf16x8 bf = *(const bf16x8*)(ebase + (((kg * 4 + lk) ^ (lrow & 7)) * 16));
      acc[0] = __builtin_amdgcn_mfma_f32_16x16x32_bf16(af[0][kg], bf, acc[0], 0, 0, 0);
      acc[1] = __builtin_amdgcn_mfma_f32_16x16x32_bf16(af[1][kg], bf, acc[1], 0, 0, 0);
      acc[2] = __builtin_amdgcn_mfma_f32_16x16x32_bf16(af[2][kg], bf, acc[2], 0, 0, 0);
      acc[3] = __builtin_amdgcn_mfma_f32_16x16x32_bf16(af[3][kg], bf, acc[3], 0, 0, 0);
    }
    // fold (codes ascending within wave; strict < keeps first index)
    const int code = w * 256 + ch * 16 + lrow;
    const float eN = eNormW[ch * 16 + lrow];
    #pragma unroll
    for (int rs = 0; rs < 4; ++rs)
      #pragma unroll
      for (int i = 0; i < 4; ++i) {
        const float sc = fmaf(-2.f, acc[rs][i], eN);
        if (sc < bb[rs][i]) { bb[rs][i] = sc; bidx[rs][i] = code; }
      }
    char* tsw = bcur; bcur = bnxt; bnxt = tsw;
  }

  // reduce over 16 code-lanes (lrow bits), then cross-wave via LDS
  #pragma unroll
  for (int rs = 0; rs < 4; ++rs)
    #pragma unroll
    for (int i = 0; i < 4; ++i)
      #pragma unroll
      for (int m = 8; m >= 1; m >>= 1) {
        const float ob = __shfl_xor(bb[rs][i], m);
        const int   oi = __shfl_xor(bidx[rs][i], m);
        if (ob < bb[rs][i] || (ob == bb[rs][i] && oi < bidx[rs][i])) { bb[rs][i] = ob; bidx[rs][i] = oi; }
      }
  if (lrow == 0) {
    #pragma unroll
    for (int rs = 0; rs < 4; ++rs)
      #pragma unroll
      for (int i = 0; i < 4; ++i) {
        float2 c2; c2.x = bb[rs][i]; c2.y = __int_as_float(bidx[rs][i]);
        cand[w * 64 + rs * 16 + lk * 4 + i] = c2;   // row = rs*16+lk*4+i
      }
  }
  __syncthreads();                           // only block-wide sync in the kernel
  if (t < 64) {
    float best = 3.4e38f; int bi = 0x7fffffff;
    #pragma unroll
    for (int wv = 0; wv < 4; ++wv) {
      const float2 c2 = cand[wv * 64 + t];
      const int ci2 = __float_as_int(c2.y);
      if (c2.x < best || (c2.x == best && ci2 < bi)) { best = c2.x; bi = ci2; }
    }
    ((int*)(ws + WS_IDX))[m0 + t] = bi;
    float d = ((const float*)(ws + WS_ZNORM))[m0 + t] + best;
    #pragma unroll
    for (int m = 32; m >= 1; m >>= 1) d += __shfl_xor(d, m);
    if (t == 0) atomicAdd((float*)(ws + WS_LOSS), d);
  }
}

// Gather quant_z (f32 exact) via padded LDS transpose; block 0 writes losses.
__global__ __launch_bounds__(256, 4)
void vq_gather(const float* __restrict__ E, const char* __restrict__ ws,
               float* __restrict__ out) {
  __shared__ float tile[256][33];
  __shared__ int idxS[32];
  const int t = threadIdx.x;
  const int n = blockIdx.x >> 5, hw0 = (blockIdx.x & 31) * 32;
  if (t < 32) idxS[t] = ((const int*)(ws + WS_IDX))[n * 1024 + hw0 + t];
  if (blockIdx.x == 0 && t == 0) {           // argmin dispatch already complete
    const float L = *((const float*)(ws + WS_LOSS)) * (1.0f / 8388608.0f);
    out[8388608] = L;
    out[8388609] = 0.25f * L;
  }
  __syncthreads();

  const int hw = t >> 3, q = t & 7;
  const float4* erow = (const float4*)(E + (size_t)idxS[hw] * CDIM);
  #pragma unroll
  for (int j = 0; j < 8; ++j) {
    const int p = q + j * 8;
    const float4 v = erow[p];
    tile[p * 4 + 0][hw] = v.x;
    tile[p * 4 + 1][hw] = v.y;
    tile[p * 4 + 2][hw] = v.z;
    tile[p * 4 + 3][hw] = v.w;
  }
  __syncthreads();

  float* obase = out + (size_t)n * (CDIM * 1024) + hw0;
  const int hw4 = (t & 7) * 4, c0 = t >> 3;
  #pragma unroll
  for (int j = 0; j < 8; ++j) {
    const int c = c0 + j * 32;
    float4 v;
    v.x = tile[c][hw4 + 0];
    v.y = tile[c][hw4 + 1];
    v.z = tile[c][hw4 + 2];
    v.w = tile[c][hw4 + 3];
    *(float4*)(obase + (size_t)c * 1024 + hw4) = v;
  }
}

extern "C" void kernel_launch(void* const* d_in, const int* in_sizes, int n_in,
                              void* d_out, int out_size, void* d_ws, size_t ws_size,
                              hipStream_t stream) {
  const float* z = (const float*)d_in[0];
  const float* E = (const float*)d_in[1];
  float* out = (float*)d_out;
  char*  ws  = (char*)d_ws;

  static const int kLdsArg = 71680;          // 4x(16K buf) + 4x1K eNorm + 2K cand
  (void)hipFuncSetAttribute((const void*)vq_argmin,
                            hipFuncAttributeMaxDynamicSharedMemorySize, kLdsArg);

  vq_pack  <<<768, 256, 0, stream>>>(z, E, ws);
  vq_argmin<<<512, 256, kLdsArg, stream>>>(ws);
  vq_gather<<<1024, 256, 0, stream>>>(E, ws, out);
}